// Round 4
// baseline (4695.224 us; speedup 1.0000x reference)
//
#include <hip/hip_runtime.h>
#include <hip/hip_bf16.h>
#include <stdint.h>

#define Bn 8
#define Tn 4096
#define En 1024
#define Hn 128
#define SCALE 0.08838834764831845f  // 1/sqrt(128)

__device__ __forceinline__ float bf2f(unsigned short v) {
    return __uint_as_float(((unsigned int)v) << 16);
}
__device__ __forceinline__ unsigned short f2bf(float f) {
    unsigned int u = __float_as_uint(f);
    u += 0x7FFFu + ((u >> 16) & 1u);
    return (unsigned short)(u >> 16);
}

// ---------------------------------------------------------------------------
// QKV projection: out = x @ W (fp32 in, fp32 accum, bf16 out). Q pre-scaled.
// grid (512, 3): x = 64-row M tile, y = which of {Q,K,V}. block 256.
// UNCHANGED (bisect discipline: only the output store convention changes
// this round, in attn_simple).
// ---------------------------------------------------------------------------
__global__ __launch_bounds__(256)
void qkv_gemm(const float* __restrict__ x,
              const float* __restrict__ Wq,
              const float* __restrict__ Wk,
              const float* __restrict__ Wv,
              unsigned short* __restrict__ Qo,
              unsigned short* __restrict__ Ko,
              unsigned short* __restrict__ Vo) {
    const int mt = blockIdx.x;
    const int which = blockIdx.y;
    const float* W = (which == 0) ? Wq : (which == 1) ? Wk : Wv;
    unsigned short* out = (which == 0) ? Qo : (which == 1) ? Ko : Vo;
    const float scale = (which == 0) ? SCALE : 1.0f;

    __shared__ float Xs[32][68];     // [kk][row], padded
    __shared__ float Ws[32 * 128];   // [kk][col]

    const int t = threadIdx.x;
    const int r0 = (t >> 5) * 8;     // 8 rows per thread
    const int c0 = (t & 31) * 4;     // 4 cols per thread

    float acc[8][4];
#pragma unroll
    for (int i = 0; i < 8; ++i)
#pragma unroll
        for (int j = 0; j < 4; ++j) acc[i][j] = 0.f;

    const int xrow = t >> 2;         // 0..63
    const int xcol = (t & 3) * 8;    // 0,8,16,24 (k-dim)

    for (int k0 = 0; k0 < En; k0 += 32) {
        __syncthreads();
        // X tile 64 rows x 32 k (fp32), stored transposed [k][row]
        {
            const float* src = x + (size_t)(mt * 64 + xrow) * En + k0 + xcol;
            float4 a0 = *(const float4*)src;
            float4 a1 = *(const float4*)(src + 4);
            Xs[xcol + 0][xrow] = a0.x; Xs[xcol + 1][xrow] = a0.y;
            Xs[xcol + 2][xrow] = a0.z; Xs[xcol + 3][xrow] = a0.w;
            Xs[xcol + 4][xrow] = a1.x; Xs[xcol + 5][xrow] = a1.y;
            Xs[xcol + 6][xrow] = a1.z; Xs[xcol + 7][xrow] = a1.w;
        }
        // W tile 32 k x 128 cols (fp32, contiguous 4096 floats)
        {
            const float* src = W + (size_t)k0 * Hn + t * 16;
            float4 w0 = *(const float4*)(src + 0);
            float4 w1 = *(const float4*)(src + 4);
            float4 w2 = *(const float4*)(src + 8);
            float4 w3 = *(const float4*)(src + 12);
            *(float4*)&Ws[t * 16 + 0]  = w0;
            *(float4*)&Ws[t * 16 + 4]  = w1;
            *(float4*)&Ws[t * 16 + 8]  = w2;
            *(float4*)&Ws[t * 16 + 12] = w3;
        }
        __syncthreads();
#pragma unroll 8
        for (int kk = 0; kk < 32; ++kk) {
            float xv[8];
            *(float4*)&xv[0] = *(const float4*)&Xs[kk][r0];
            *(float4*)&xv[4] = *(const float4*)&Xs[kk][r0 + 4];
            float4 wv = *(const float4*)&Ws[kk * 128 + c0];
#pragma unroll
            for (int i = 0; i < 8; ++i) {
                acc[i][0] += xv[i] * wv.x;
                acc[i][1] += xv[i] * wv.y;
                acc[i][2] += xv[i] * wv.z;
                acc[i][3] += xv[i] * wv.w;
            }
        }
    }
#pragma unroll
    for (int i = 0; i < 8; ++i) {
        union { uint2 u; unsigned short s[4]; } pk;
#pragma unroll
        for (int j = 0; j < 4; ++j) pk.s[j] = f2bf(acc[i][j] * scale);
        *(uint2*)(out + (size_t)(mt * 64 + r0 + i) * Hn + c0) = pk.u;
    }
}

// ---------------------------------------------------------------------------
// Diagnostic attention: one wave per query row. No LDS, no inter-wave
// coupling. Lane l owns output dims {2l, 2l+1}. Online softmax with
// wave-uniform scalar state. OUTPUT NOW FP32 (the one change this round).
// ---------------------------------------------------------------------------
__global__ __launch_bounds__(256)
void attn_simple(const unsigned short* __restrict__ Qb,
                 const unsigned short* __restrict__ Kb,
                 const unsigned short* __restrict__ Vb,
                 float* __restrict__ out) {
    const int blk = blockIdx.x;          // 0..8191
    const int b = blk & 7;               // batch -> XCD-resident K/V
    const int ig = blk >> 3;             // 0..1023
    const int w = threadIdx.x >> 6;      // wave 0..3
    const int lane = threadIdx.x & 63;
    const int t = (1023 - ig) * 4 + w;   // query row, reversed dispatch
    const int d0 = lane * 2;
    const size_t base = (size_t)b * Tn * Hn;

    // q for this row (bf16, pre-scaled by 1/sqrt(H) in projection)
    const unsigned short* qp = Qb + base + (size_t)t * Hn + d0;
    const float q0 = bf2f(qp[0]);
    const float q1 = bf2f(qp[1]);

    float m = -1e30f, l = 0.f, o0 = 0.f, o1 = 0.f;

    const unsigned short* kp = Kb + base + d0;
    const unsigned short* vp = Vb + base + d0;
    for (int s = 0; s <= t; ++s) {
        const float k0 = bf2f(kp[0]);
        const float k1 = bf2f(kp[1]);
        const float v0 = bf2f(vp[0]);
        const float v1 = bf2f(vp[1]);
        kp += Hn; vp += Hn;

        float part = q0 * k0 + q1 * k1;
        part += __shfl_xor(part, 1);
        part += __shfl_xor(part, 2);
        part += __shfl_xor(part, 4);
        part += __shfl_xor(part, 8);
        part += __shfl_xor(part, 16);
        part += __shfl_xor(part, 32);
        const float dot = part;          // wave-uniform

        if (dot > m) {                   // wave-uniform branch
            const float alpha = __expf(m - dot);
            l *= alpha; o0 *= alpha; o1 *= alpha;
            m = dot;
        }
        const float p = __expf(dot - m);
        l += p;
        o0 += p * v0;
        o1 += p * v1;
    }

    const float inv = 1.f / l;
    float2 r = make_float2(o0 * inv, o1 * inv);
    *(float2*)(out + base + (size_t)t * Hn + d0) = r;
}

// ---------------------------------------------------------------------------
extern "C" void kernel_launch(void* const* d_in, const int* in_sizes, int n_in,
                              void* d_out, int out_size, void* d_ws, size_t ws_size,
                              hipStream_t stream) {
    const float* x  = (const float*)d_in[0];
    const float* Wq = (const float*)d_in[1];
    const float* Wk = (const float*)d_in[2];
    const float* Wv = (const float*)d_in[3];
    float* o = (float*)d_out;            // OUTPUT IS FP32 (hypothesis this round)

    unsigned short* Qb = (unsigned short*)d_ws;                 // (B*T, H) bf16
    unsigned short* Kb = Qb + (size_t)Bn * Tn * Hn;
    unsigned short* Vb = Kb + (size_t)Bn * Tn * Hn;

    qkv_gemm<<<dim3(512, 3), 256, 0, stream>>>(x, Wq, Wk, Wv, Qb, Kb, Vb);
    attn_simple<<<dim3(8192), 256, 0, stream>>>(Qb, Kb, Vb, o);
}

// Round 5
// 2261.528 us; speedup vs baseline: 2.0761x; 2.0761x over previous
//
#include <hip/hip_runtime.h>
#include <hip/hip_bf16.h>
#include <stdint.h>

#define Bn 8
#define Tn 4096
#define En 1024
#define Hn 128
#define SCALE 0.08838834764831845f  // 1/sqrt(128)

__device__ __forceinline__ float bf2f(unsigned short v) {
    return __uint_as_float(((unsigned int)v) << 16);
}
__device__ __forceinline__ unsigned short f2bf(float f) {
    unsigned int u = __float_as_uint(f);
    u += 0x7FFFu + ((u >> 16) & 1u);
    return (unsigned short)(u >> 16);
}

// ---------------------------------------------------------------------------
// QKV projection: out = x @ W (fp32 in, fp32 accum, bf16 out). Q pre-scaled.
// grid (512, 3). UNCHANGED from the passing round-4 build.
// ---------------------------------------------------------------------------
__global__ __launch_bounds__(256)
void qkv_gemm(const float* __restrict__ x,
              const float* __restrict__ Wq,
              const float* __restrict__ Wk,
              const float* __restrict__ Wv,
              unsigned short* __restrict__ Qo,
              unsigned short* __restrict__ Ko,
              unsigned short* __restrict__ Vo) {
    const int mt = blockIdx.x;
    const int which = blockIdx.y;
    const float* W = (which == 0) ? Wq : (which == 1) ? Wk : Wv;
    unsigned short* out = (which == 0) ? Qo : (which == 1) ? Ko : Vo;
    const float scale = (which == 0) ? SCALE : 1.0f;

    __shared__ float Xs[32][68];     // [kk][row], padded
    __shared__ float Ws[32 * 128];   // [kk][col]

    const int t = threadIdx.x;
    const int r0 = (t >> 5) * 8;     // 8 rows per thread
    const int c0 = (t & 31) * 4;     // 4 cols per thread

    float acc[8][4];
#pragma unroll
    for (int i = 0; i < 8; ++i)
#pragma unroll
        for (int j = 0; j < 4; ++j) acc[i][j] = 0.f;

    const int xrow = t >> 2;         // 0..63
    const int xcol = (t & 3) * 8;    // 0,8,16,24 (k-dim)

    for (int k0 = 0; k0 < En; k0 += 32) {
        __syncthreads();
        {
            const float* src = x + (size_t)(mt * 64 + xrow) * En + k0 + xcol;
            float4 a0 = *(const float4*)src;
            float4 a1 = *(const float4*)(src + 4);
            Xs[xcol + 0][xrow] = a0.x; Xs[xcol + 1][xrow] = a0.y;
            Xs[xcol + 2][xrow] = a0.z; Xs[xcol + 3][xrow] = a0.w;
            Xs[xcol + 4][xrow] = a1.x; Xs[xcol + 5][xrow] = a1.y;
            Xs[xcol + 6][xrow] = a1.z; Xs[xcol + 7][xrow] = a1.w;
        }
        {
            const float* src = W + (size_t)k0 * Hn + t * 16;
            float4 w0 = *(const float4*)(src + 0);
            float4 w1 = *(const float4*)(src + 4);
            float4 w2 = *(const float4*)(src + 8);
            float4 w3 = *(const float4*)(src + 12);
            *(float4*)&Ws[t * 16 + 0]  = w0;
            *(float4*)&Ws[t * 16 + 4]  = w1;
            *(float4*)&Ws[t * 16 + 8]  = w2;
            *(float4*)&Ws[t * 16 + 12] = w3;
        }
        __syncthreads();
#pragma unroll 8
        for (int kk = 0; kk < 32; ++kk) {
            float xv[8];
            *(float4*)&xv[0] = *(const float4*)&Xs[kk][r0];
            *(float4*)&xv[4] = *(const float4*)&Xs[kk][r0 + 4];
            float4 wv = *(const float4*)&Ws[kk * 128 + c0];
#pragma unroll
            for (int i = 0; i < 8; ++i) {
                acc[i][0] += xv[i] * wv.x;
                acc[i][1] += xv[i] * wv.y;
                acc[i][2] += xv[i] * wv.z;
                acc[i][3] += xv[i] * wv.w;
            }
        }
    }
#pragma unroll
    for (int i = 0; i < 8; ++i) {
        union { uint2 u; unsigned short s[4]; } pk;
#pragma unroll
        for (int j = 0; j < 4; ++j) pk.s[j] = f2bf(acc[i][j] * scale);
        *(uint2*)(out + (size_t)(mt * 64 + r0 + i) * Hn + c0) = pk.u;
    }
}

// ---------------------------------------------------------------------------
// Flash-style causal attention (validated logic from R2; store now fp32).
// grid (64, 8): x -> q-tile (reversed, heavy-first), y -> b. block 256.
// ---------------------------------------------------------------------------
__global__ __launch_bounds__(256)
void flash_attn(const unsigned short* __restrict__ Qb,
                const unsigned short* __restrict__ Kb,
                const unsigned short* __restrict__ Vb,
                float* __restrict__ out) {
    const int qt = gridDim.x - 1 - blockIdx.x;  // heavy blocks first
    const int b = blockIdx.y;

    __shared__ float Qs[64][132];
    __shared__ float Ks[64][132];
    __shared__ float Vs[64][128];
    __shared__ float Ss[64][68];

    const int t = threadIdx.x;
    const int i0 = (t >> 4) * 4;   // 4 S/O rows
    const int j0 = (t & 15) * 4;   // 4 S cols
    const int d0 = (t & 15) * 8;   // 8 O dims

    // Load Q tile (already scaled by 1/sqrt(H) in projection)
    {
        const unsigned short* src = Qb + ((size_t)b * Tn + (size_t)qt * 64) * Hn;
#pragma unroll
        for (int i = 0; i < 4; ++i) {
            int idx = (t + i * 256) * 8;
            uint4 raw = *(const uint4*)(src + idx);
            const unsigned short* s = (const unsigned short*)&raw;
            int row = idx >> 7, col = idx & 127;
#pragma unroll
            for (int e = 0; e < 8; ++e) Qs[row][col + e] = bf2f(s[e]);
        }
    }

    float o[4][8];
    float m_[4], l_[4];
#pragma unroll
    for (int i = 0; i < 4; ++i) {
        m_[i] = -1e30f; l_[i] = 0.f;
#pragma unroll
        for (int d = 0; d < 8; ++d) o[i][d] = 0.f;
    }

    for (int kt = 0; kt <= qt; ++kt) {
        __syncthreads();
        {
            const unsigned short* ksrc = Kb + ((size_t)b * Tn + (size_t)kt * 64) * Hn;
            const unsigned short* vsrc = Vb + ((size_t)b * Tn + (size_t)kt * 64) * Hn;
#pragma unroll
            for (int i = 0; i < 4; ++i) {
                int idx = (t + i * 256) * 8;
                int row = idx >> 7, col = idx & 127;
                uint4 kr = *(const uint4*)(ksrc + idx);
                uint4 vr = *(const uint4*)(vsrc + idx);
                const unsigned short* ks = (const unsigned short*)&kr;
                const unsigned short* vs = (const unsigned short*)&vr;
#pragma unroll
                for (int e = 0; e < 8; ++e) Ks[row][col + e] = bf2f(ks[e]);
#pragma unroll
                for (int e = 0; e < 8; ++e) Vs[row][col + e] = bf2f(vs[e]);
            }
        }
        __syncthreads();

        // S = Q . K^T, 4x4 per thread
        float s[4][4];
#pragma unroll
        for (int i = 0; i < 4; ++i)
#pragma unroll
            for (int j = 0; j < 4; ++j) s[i][j] = 0.f;

        for (int e4 = 0; e4 < 32; ++e4) {
            float4 q4[4], k4[4];
#pragma unroll
            for (int i = 0; i < 4; ++i) q4[i] = *(const float4*)&Qs[i0 + i][e4 * 4];
#pragma unroll
            for (int j = 0; j < 4; ++j) k4[j] = *(const float4*)&Ks[j0 + j][e4 * 4];
#pragma unroll
            for (int i = 0; i < 4; ++i)
#pragma unroll
                for (int j = 0; j < 4; ++j)
                    s[i][j] += q4[i].x * k4[j].x + q4[i].y * k4[j].y
                             + q4[i].z * k4[j].z + q4[i].w * k4[j].w;
        }
        if (kt == qt) {
#pragma unroll
            for (int i = 0; i < 4; ++i)
#pragma unroll
                for (int j = 0; j < 4; ++j)
                    if (j0 + j > i0 + i) s[i][j] = -1e30f;
        }
#pragma unroll
        for (int i = 0; i < 4; ++i) {
            *(float4*)&Ss[i0 + i][j0] = make_float4(s[i][0], s[i][1], s[i][2], s[i][3]);
        }
        __syncthreads();

        // Online softmax update for rows i0..i0+3
        float mn[4], alpha[4], lsum[4];
#pragma unroll
        for (int i = 0; i < 4; ++i) {
            float mv = m_[i];
#pragma unroll
            for (int jj = 0; jj < 16; ++jj) {
                float4 sv = *(const float4*)&Ss[i0 + i][jj * 4];
                mv = fmaxf(mv, fmaxf(fmaxf(sv.x, sv.y), fmaxf(sv.z, sv.w)));
            }
            mn[i] = mv;
            alpha[i] = __expf(m_[i] - mv);
            lsum[i] = 0.f;
#pragma unroll
            for (int d = 0; d < 8; ++d) o[i][d] *= alpha[i];
        }
        for (int j = 0; j < 64; ++j) {
            float4 v0 = *(const float4*)&Vs[j][d0];
            float4 v1 = *(const float4*)&Vs[j][d0 + 4];
#pragma unroll
            for (int i = 0; i < 4; ++i) {
                float p = __expf(Ss[i0 + i][j] - mn[i]);
                lsum[i] += p;
                o[i][0] += p * v0.x; o[i][1] += p * v0.y;
                o[i][2] += p * v0.z; o[i][3] += p * v0.w;
                o[i][4] += p * v1.x; o[i][5] += p * v1.y;
                o[i][6] += p * v1.z; o[i][7] += p * v1.w;
            }
        }
#pragma unroll
        for (int i = 0; i < 4; ++i) {
            l_[i] = l_[i] * alpha[i] + lsum[i];
            m_[i] = mn[i];
        }
    }

    // Epilogue: O /= l, write fp32
#pragma unroll
    for (int i = 0; i < 4; ++i) {
        float inv = 1.f / l_[i];
        float* dst = out + ((size_t)b * Tn + (size_t)qt * 64 + i0 + i) * Hn + d0;
        *(float4*)dst       = make_float4(o[i][0] * inv, o[i][1] * inv, o[i][2] * inv, o[i][3] * inv);
        *(float4*)(dst + 4) = make_float4(o[i][4] * inv, o[i][5] * inv, o[i][6] * inv, o[i][7] * inv);
    }
}

// ---------------------------------------------------------------------------
extern "C" void kernel_launch(void* const* d_in, const int* in_sizes, int n_in,
                              void* d_out, int out_size, void* d_ws, size_t ws_size,
                              hipStream_t stream) {
    const float* x  = (const float*)d_in[0];
    const float* Wq = (const float*)d_in[1];
    const float* Wk = (const float*)d_in[2];
    const float* Wv = (const float*)d_in[3];
    float* o = (float*)d_out;            // output fp32 (verified round 4)

    unsigned short* Qb = (unsigned short*)d_ws;                 // (B*T, H) bf16
    unsigned short* Kb = Qb + (size_t)Bn * Tn * Hn;
    unsigned short* Vb = Kb + (size_t)Bn * Tn * Hn;

    qkv_gemm<<<dim3(512, 3), 256, 0, stream>>>(x, Wq, Wk, Wv, Qb, Kb, Vb);
    flash_attn<<<dim3(64, 8), 256, 0, stream>>>(Qb, Kb, Vb, o);
}

// Round 6
// 658.883 us; speedup vs baseline: 7.1260x; 3.4324x over previous
//
#include <hip/hip_runtime.h>
#include <hip/hip_bf16.h>
#include <stdint.h>

#define Bn 8
#define Tn 4096
#define En 1024
#define Hn 128
#define SCALE 0.08838834764831845f  // 1/sqrt(128)

typedef __attribute__((ext_vector_type(8))) short bf16x8;
typedef __attribute__((ext_vector_type(4))) float f32x4;

__device__ __forceinline__ float bf2f(unsigned short v) {
    return __uint_as_float(((unsigned int)v) << 16);
}
__device__ __forceinline__ unsigned short f2bf(float f) {
    unsigned int u = __float_as_uint(f);
    u += 0x7FFFu + ((u >> 16) & 1u);
    return (unsigned short)(u >> 16);
}

// ---------------------------------------------------------------------------
// QKV projection: out = x @ W (fp32 in, fp32 accum, bf16 out). Q pre-scaled.
// grid (512, 3). UNCHANGED from the passing round-5 build.
// ---------------------------------------------------------------------------
__global__ __launch_bounds__(256)
void qkv_gemm(const float* __restrict__ x,
              const float* __restrict__ Wq,
              const float* __restrict__ Wk,
              const float* __restrict__ Wv,
              unsigned short* __restrict__ Qo,
              unsigned short* __restrict__ Ko,
              unsigned short* __restrict__ Vo) {
    const int mt = blockIdx.x;
    const int which = blockIdx.y;
    const float* W = (which == 0) ? Wq : (which == 1) ? Wk : Wv;
    unsigned short* out = (which == 0) ? Qo : (which == 1) ? Ko : Vo;
    const float scale = (which == 0) ? SCALE : 1.0f;

    __shared__ float Xs[32][68];     // [kk][row], padded
    __shared__ float Ws[32 * 128];   // [kk][col]

    const int t = threadIdx.x;
    const int r0 = (t >> 5) * 8;     // 8 rows per thread
    const int c0 = (t & 31) * 4;     // 4 cols per thread

    float acc[8][4];
#pragma unroll
    for (int i = 0; i < 8; ++i)
#pragma unroll
        for (int j = 0; j < 4; ++j) acc[i][j] = 0.f;

    const int xrow = t >> 2;         // 0..63
    const int xcol = (t & 3) * 8;    // 0,8,16,24 (k-dim)

    for (int k0 = 0; k0 < En; k0 += 32) {
        __syncthreads();
        {
            const float* src = x + (size_t)(mt * 64 + xrow) * En + k0 + xcol;
            float4 a0 = *(const float4*)src;
            float4 a1 = *(const float4*)(src + 4);
            Xs[xcol + 0][xrow] = a0.x; Xs[xcol + 1][xrow] = a0.y;
            Xs[xcol + 2][xrow] = a0.z; Xs[xcol + 3][xrow] = a0.w;
            Xs[xcol + 4][xrow] = a1.x; Xs[xcol + 5][xrow] = a1.y;
            Xs[xcol + 6][xrow] = a1.z; Xs[xcol + 7][xrow] = a1.w;
        }
        {
            const float* src = W + (size_t)k0 * Hn + t * 16;
            float4 w0 = *(const float4*)(src + 0);
            float4 w1 = *(const float4*)(src + 4);
            float4 w2 = *(const float4*)(src + 8);
            float4 w3 = *(const float4*)(src + 12);
            *(float4*)&Ws[t * 16 + 0]  = w0;
            *(float4*)&Ws[t * 16 + 4]  = w1;
            *(float4*)&Ws[t * 16 + 8]  = w2;
            *(float4*)&Ws[t * 16 + 12] = w3;
        }
        __syncthreads();
#pragma unroll 8
        for (int kk = 0; kk < 32; ++kk) {
            float xv[8];
            *(float4*)&xv[0] = *(const float4*)&Xs[kk][r0];
            *(float4*)&xv[4] = *(const float4*)&Xs[kk][r0 + 4];
            float4 wv = *(const float4*)&Ws[kk * 128 + c0];
#pragma unroll
            for (int i = 0; i < 8; ++i) {
                acc[i][0] += xv[i] * wv.x;
                acc[i][1] += xv[i] * wv.y;
                acc[i][2] += xv[i] * wv.z;
                acc[i][3] += xv[i] * wv.w;
            }
        }
    }
#pragma unroll
    for (int i = 0; i < 8; ++i) {
        union { uint2 u; unsigned short s[4]; } pk;
#pragma unroll
        for (int j = 0; j < 4; ++j) pk.s[j] = f2bf(acc[i][j] * scale);
        *(uint2*)(out + (size_t)(mt * 64 + r0 + i) * Hn + c0) = pk.u;
    }
}

// ---------------------------------------------------------------------------
// MFMA flash attention. Block = 256 thr (4 waves), q-tile 64 rows, wave w
// owns q-rows w*16..w*16+15. S^T = K.Q^T (C-layout: q = lane&15), online
// softmax via shfl over quads, O^T = V^T.P^T with per-wave P LDS roundtrip.
// LDS 52 KB -> 3 blocks/CU. grid (64,8): qt paired so co-resident blocks
// sum to ~constant work.
// ---------------------------------------------------------------------------
__global__ __launch_bounds__(256)
void flash_mfma(const unsigned short* __restrict__ Qb,
                const unsigned short* __restrict__ Kb,
                const unsigned short* __restrict__ Vb,
                float* __restrict__ out) {
    const int bx = blockIdx.x;
    const int by = blockIdx.y;                    // batch
    const int qt = (by & 4) ? bx : (63 - bx);     // heavy/light pairing
    const int t = threadIdx.x;
    const int w = t >> 6;
    const int lane = t & 63;
    const int quad = lane >> 4;
    const int l16 = lane & 15;

    __shared__ alignas(16) unsigned short pool[26624];   // 52 KB
    unsigned short* Qs = pool;            // [64][136] bf16
    unsigned short* Ks = pool + 8704;     // [64][136] bf16
    unsigned short* Vt = pool + 17408;    // [128][72] bf16 (V transposed)
    unsigned short* Ps = pool + w * 1152; // per-wave [16][72], overlays Qs
    float* Os = (float*)pool;             // [64][132] fp32 (epilogue overlay)

    const size_t gbase = (size_t)by * ((size_t)Tn * Hn);

    // ---- stage Q tile ----
    {
        const unsigned short* src = Qb + gbase + (size_t)(qt * 64) * Hn;
#pragma unroll
        for (int i = 0; i < 4; ++i) {
            int idx = t + i * 256;
            int row = idx >> 4, col = (idx & 15) * 8;
            *(uint4*)&Qs[row * 136 + col] = *(const uint4*)&src[row * 128 + col];
        }
    }
    __syncthreads();

    // hoist Q B-frags (Q^T): lane holds Q[q=l16][d=ks*32+quad*8+j]
    bf16x8 qf[4];
#pragma unroll
    for (int ks = 0; ks < 4; ++ks)
        qf[ks] = *(const bf16x8*)&Qs[(w * 16 + l16) * 136 + ks * 32 + quad * 8];

    f32x4 acc_o[8];
#pragma unroll
    for (int i = 0; i < 8; ++i) acc_o[i] = (f32x4){0.f, 0.f, 0.f, 0.f};
    float m_run = -1e30f, l_run = 0.f;

    for (int kt = 0; kt <= qt; ++kt) {
        __syncthreads();   // also separates pre-loop Q-frag reads from Ps writes
        {
            // stage K (row-major)
            const unsigned short* ksrc = Kb + gbase + (size_t)(kt * 64) * Hn;
#pragma unroll
            for (int i = 0; i < 4; ++i) {
                int idx = t + i * 256;
                int row = idx >> 4, col = (idx & 15) * 8;
                *(uint4*)&Ks[row * 136 + col] = *(const uint4*)&ksrc[row * 128 + col];
            }
            // stage V transposed: Vt[d][s], paired-s b32 writes (conflict-free)
            const unsigned short* vsrc = Vb + gbase + (size_t)(kt * 64) * Hn;
            int s0 = (t & 31) * 2, d0 = (t >> 5) * 16;
            uint4 ra = *(const uint4*)&vsrc[s0 * 128 + d0];
            uint4 rb = *(const uint4*)&vsrc[s0 * 128 + d0 + 8];
            uint4 rc = *(const uint4*)&vsrc[(s0 + 1) * 128 + d0];
            uint4 rd = *(const uint4*)&vsrc[(s0 + 1) * 128 + d0 + 8];
            const unsigned short* pa = (const unsigned short*)&ra;
            const unsigned short* pb = (const unsigned short*)&rb;
            const unsigned short* pc = (const unsigned short*)&rc;
            const unsigned short* pd = (const unsigned short*)&rd;
#pragma unroll
            for (int dd = 0; dd < 8; ++dd)
                *(unsigned int*)&Vt[(d0 + dd) * 72 + s0] =
                    (unsigned int)pa[dd] | ((unsigned int)pc[dd] << 16);
#pragma unroll
            for (int dd = 0; dd < 8; ++dd)
                *(unsigned int*)&Vt[(d0 + 8 + dd) * 72 + s0] =
                    (unsigned int)pb[dd] | ((unsigned int)pd[dd] << 16);
        }
        __syncthreads();

        const bool diag = (kt == qt);
        // S^T = K.Q^T ; lane holds S[q=l16][s=st*16+quad*4+r]
        f32x4 sa[4];
#pragma unroll
        for (int st = 0; st < 4; ++st) {
            if (diag && st > w) {
                sa[st] = (f32x4){-1e30f, -1e30f, -1e30f, -1e30f};  // fully masked
            } else {
                f32x4 c = (f32x4){0.f, 0.f, 0.f, 0.f};
#pragma unroll
                for (int ks = 0; ks < 4; ++ks) {
                    bf16x8 kf = *(const bf16x8*)&Ks[(st * 16 + l16) * 136 + ks * 32 + quad * 8];
                    c = __builtin_amdgcn_mfma_f32_16x16x32_bf16(kf, qf[ks], c, 0, 0, 0);
                }
                if (diag && st == w) {
#pragma unroll
                    for (int r = 0; r < 4; ++r)
                        if (quad * 4 + r > l16) c[r] = -1e30f;
                }
                sa[st] = c;
            }
        }

        // online softmax for q-row l16 (state replicated across the 4 quads)
        float mloc = -1e30f;
#pragma unroll
        for (int st = 0; st < 4; ++st)
#pragma unroll
            for (int r = 0; r < 4; ++r) mloc = fmaxf(mloc, sa[st][r]);
        mloc = fmaxf(mloc, __shfl_xor(mloc, 16));
        mloc = fmaxf(mloc, __shfl_xor(mloc, 32));
        const float m_new = fmaxf(m_run, mloc);
        const float alpha = __expf(m_run - m_new);
        float p[4][4];
        float lsum = 0.f;
#pragma unroll
        for (int st = 0; st < 4; ++st)
#pragma unroll
            for (int r = 0; r < 4; ++r) {
                p[st][r] = __expf(sa[st][r] - m_new);
                lsum += p[st][r];
            }
        lsum += __shfl_xor(lsum, 16);
        lsum += __shfl_xor(lsum, 32);
        l_run = l_run * alpha + lsum;
        m_run = m_new;
#pragma unroll
        for (int i = 0; i < 8; ++i) acc_o[i] *= alpha;

        // P (C-layout) -> per-wave LDS -> P^T B-frags (same-wave, no barrier)
#pragma unroll
        for (int st = 0; st < 4; ++st) {
            uint2 pk;
            pk.x = (unsigned int)f2bf(p[st][0]) | ((unsigned int)f2bf(p[st][1]) << 16);
            pk.y = (unsigned int)f2bf(p[st][2]) | ((unsigned int)f2bf(p[st][3]) << 16);
            *(uint2*)&Ps[l16 * 72 + st * 16 + quad * 4] = pk;
        }
        bf16x8 pf0 = *(const bf16x8*)&Ps[l16 * 72 + quad * 8];
        bf16x8 pf1 = *(const bf16x8*)&Ps[l16 * 72 + 32 + quad * 8];

        // O^T += V^T . P^T
#pragma unroll
        for (int dt = 0; dt < 8; ++dt) {
            bf16x8 vf0 = *(const bf16x8*)&Vt[(dt * 16 + l16) * 72 + quad * 8];
            acc_o[dt] = __builtin_amdgcn_mfma_f32_16x16x32_bf16(vf0, pf0, acc_o[dt], 0, 0, 0);
            bf16x8 vf1 = *(const bf16x8*)&Vt[(dt * 16 + l16) * 72 + 32 + quad * 8];
            acc_o[dt] = __builtin_amdgcn_mfma_f32_16x16x32_bf16(vf1, pf1, acc_o[dt], 0, 0, 0);
        }
    }

    // epilogue: O^T regs -> LDS (transpose) -> coalesced fp32 stores
    __syncthreads();
    const float inv = 1.f / l_run;
#pragma unroll
    for (int dt = 0; dt < 8; ++dt) {
        f32x4 v = acc_o[dt] * inv;
        *(f32x4*)&Os[(w * 16 + l16) * 132 + dt * 16 + quad * 4] = v;
    }
    __syncthreads();
    float* dst = out + gbase + (size_t)(qt * 64) * Hn;
#pragma unroll
    for (int i = 0; i < 8; ++i) {
        int idx = (t + i * 256) * 4;
        int row = idx >> 7, col = idx & 127;
        *(float4*)&dst[row * 128 + col] = *(const float4*)&Os[row * 132 + col];
    }
}

// ---------------------------------------------------------------------------
extern "C" void kernel_launch(void* const* d_in, const int* in_sizes, int n_in,
                              void* d_out, int out_size, void* d_ws, size_t ws_size,
                              hipStream_t stream) {
    const float* x  = (const float*)d_in[0];
    const float* Wq = (const float*)d_in[1];
    const float* Wk = (const float*)d_in[2];
    const float* Wv = (const float*)d_in[3];
    float* o = (float*)d_out;            // output fp32 (verified round 4)

    unsigned short* Qb = (unsigned short*)d_ws;                 // (B*T, H) bf16
    unsigned short* Kb = Qb + (size_t)Bn * Tn * Hn;
    unsigned short* Vb = Kb + (size_t)Bn * Tn * Hn;

    qkv_gemm<<<dim3(512, 3), 256, 0, stream>>>(x, Wq, Wk, Wv, Qb, Kb, Vb);
    flash_mfma<<<dim3(64, 8), 256, 0, stream>>>(Qb, Kb, Vb, o);
}

// Round 7
// 460.918 us; speedup vs baseline: 10.1867x; 1.4295x over previous
//
#include <hip/hip_runtime.h>
#include <hip/hip_bf16.h>
#include <stdint.h>

#define Bn 8
#define Tn 4096
#define En 1024
#define Hn 128
#define SCALE 0.08838834764831845f  // 1/sqrt(128)

typedef __attribute__((ext_vector_type(8))) short bf16x8;
typedef __attribute__((ext_vector_type(4))) float f32x4;

__device__ __forceinline__ float bf2f(unsigned short v) {
    return __uint_as_float(((unsigned int)v) << 16);
}
__device__ __forceinline__ unsigned short f2bf(float f) {
    unsigned int u = __float_as_uint(f);
    u += 0x7FFFu + ((u >> 16) & 1u);
    return (unsigned short)(u >> 16);
}
// RNE pack of two fp32 -> packed bf16x2 (v_cvt_pk_bf16_f32 on gfx950)
__device__ __forceinline__ unsigned int pkbf(float a, float b) {
    __hip_bfloat162 h = __float22bfloat162_rn(make_float2(a, b));
    union { __hip_bfloat162 h2; unsigned int u; } cv;
    cv.h2 = h;
    return cv.u;
}

// ---------------------------------------------------------------------------
// QKV projection via MFMA: out = x @ W (fp32 in, bf16 MFMA, bf16 out).
// grid (3, 256): x = which {Q,K,V} (fastest -> same-mt triplet adjacent for
// L2 reuse of x), y = 128-row M tile. block 256 = 4 waves; wave w owns rows
// [w*32, w*32+32). BK=64. LDS: Xs[128][72] bf16 + Wt[128][72] bf16 = 36 KB
// -> 3 blocks/CU resident (grid is exactly 3 blocks/CU).
// ---------------------------------------------------------------------------
__global__ __launch_bounds__(256, 3)
void qkv_mfma(const float* __restrict__ x,
              const float* __restrict__ Wq,
              const float* __restrict__ Wk,
              const float* __restrict__ Wv,
              unsigned short* __restrict__ Qo,
              unsigned short* __restrict__ Ko,
              unsigned short* __restrict__ Vo) {
    const int which = blockIdx.x;
    const int mt = blockIdx.y;
    const float* W = (which == 0) ? Wq : (which == 1) ? Wk : Wv;
    unsigned short* out = (which == 0) ? Qo : (which == 1) ? Ko : Vo;
    const float scale = (which == 0) ? SCALE : 1.0f;

    __shared__ alignas(16) unsigned short Xs[128 * 72];  // [m][k] bf16, pad 72
    __shared__ alignas(16) unsigned short Wt[128 * 72];  // [n][k] bf16 (transposed)

    const int t = threadIdx.x;
    const int w = t >> 6;
    const int lane = t & 63;
    const int quad = lane >> 4;
    const int l16 = lane & 15;

    // staging coords
    const int xrow = t >> 1;              // 0..127
    const int xkc = (t & 1) * 32;         // 0 or 32
    const int ws0 = (t & 31) * 2;         // k pair 0..62
    const int wd0 = (t >> 5) * 16;        // n group 0..112

    f32x4 acc[2][8];
#pragma unroll
    for (int mi = 0; mi < 2; ++mi)
#pragma unroll
        for (int nst = 0; nst < 8; ++nst) acc[mi][nst] = (f32x4){0.f, 0.f, 0.f, 0.f};

    for (int kt = 0; kt < 16; ++kt) {
        __syncthreads();
        // ---- stage x tile: 128 rows x 64 k, fp32 -> bf16, [m][k] ----
        {
            const float* src = x + (size_t)(mt * 128 + xrow) * En + kt * 64 + xkc;
            float4 f[8];
#pragma unroll
            for (int i = 0; i < 8; ++i) f[i] = *(const float4*)(src + i * 4);
            unsigned int u[16];
#pragma unroll
            for (int i = 0; i < 8; ++i) {
                u[2 * i]     = pkbf(f[i].x, f[i].y);
                u[2 * i + 1] = pkbf(f[i].z, f[i].w);
            }
#pragma unroll
            for (int i = 0; i < 4; ++i)
                *(uint4*)&Xs[xrow * 72 + xkc + i * 8] = ((const uint4*)u)[i];
        }
        // ---- stage W tile transposed: W[k][n] -> Wt[n][k], fp32 -> bf16 ----
        {
            const float* w0 = W + (size_t)(kt * 64 + ws0) * Hn + wd0;
            const float* w1 = w0 + Hn;
            float4 a0 = *(const float4*)(w0 + 0),  a1 = *(const float4*)(w0 + 4);
            float4 a2 = *(const float4*)(w0 + 8),  a3 = *(const float4*)(w0 + 12);
            float4 b0 = *(const float4*)(w1 + 0),  b1 = *(const float4*)(w1 + 4);
            float4 b2 = *(const float4*)(w1 + 8),  b3 = *(const float4*)(w1 + 12);
            const float* av = (const float*)&a0;   // a0..a3 contiguous
            const float* bv = (const float*)&b0;
            float ax[16], bx[16];
            *(float4*)&ax[0] = a0; *(float4*)&ax[4] = a1; *(float4*)&ax[8] = a2; *(float4*)&ax[12] = a3;
            *(float4*)&bx[0] = b0; *(float4*)&bx[4] = b1; *(float4*)&bx[8] = b2; *(float4*)&bx[12] = b3;
            (void)av; (void)bv;
#pragma unroll
            for (int dd = 0; dd < 16; ++dd)
                *(unsigned int*)&Wt[(wd0 + dd) * 72 + ws0] = pkbf(ax[dd], bx[dd]);
        }
        __syncthreads();

        // ---- MFMA: 32 per wave per k-tile ----
#pragma unroll
        for (int ks = 0; ks < 2; ++ks) {
            bf16x8 af[2];
#pragma unroll
            for (int mi = 0; mi < 2; ++mi)
                af[mi] = *(const bf16x8*)&Xs[(w * 32 + mi * 16 + l16) * 72 + ks * 32 + quad * 8];
#pragma unroll
            for (int nst = 0; nst < 8; ++nst) {
                bf16x8 bfr = *(const bf16x8*)&Wt[(nst * 16 + l16) * 72 + ks * 32 + quad * 8];
                // mfma(B=W, A=x): C col (lane&15) = m, C row (quad*4+reg) = n
                acc[0][nst] = __builtin_amdgcn_mfma_f32_16x16x32_bf16(bfr, af[0], acc[0][nst], 0, 0, 0);
                acc[1][nst] = __builtin_amdgcn_mfma_f32_16x16x32_bf16(bfr, af[1], acc[1][nst], 0, 0, 0);
            }
        }
    }

    // ---- epilogue: lane holds m = l16, n = nst*16 + quad*4 + r (4 consecutive) ----
#pragma unroll
    for (int mi = 0; mi < 2; ++mi) {
        const size_t rowbase = (size_t)(mt * 128 + w * 32 + mi * 16 + l16) * Hn;
#pragma unroll
        for (int nst = 0; nst < 8; ++nst) {
            f32x4 v = acc[mi][nst];
            uint2 pk;
            pk.x = pkbf(v[0] * scale, v[1] * scale);
            pk.y = pkbf(v[2] * scale, v[3] * scale);
            *(uint2*)(out + rowbase + nst * 16 + quad * 4) = pk;
        }
    }
}

// ---------------------------------------------------------------------------
// MFMA flash attention — UNCHANGED from passing round 6 (~300 us).
// ---------------------------------------------------------------------------
__global__ __launch_bounds__(256)
void flash_mfma(const unsigned short* __restrict__ Qb,
                const unsigned short* __restrict__ Kb,
                const unsigned short* __restrict__ Vb,
                float* __restrict__ out) {
    const int bx = blockIdx.x;
    const int by = blockIdx.y;                    // batch
    const int qt = (by & 4) ? bx : (63 - bx);     // heavy/light pairing
    const int t = threadIdx.x;
    const int w = t >> 6;
    const int lane = t & 63;
    const int quad = lane >> 4;
    const int l16 = lane & 15;

    __shared__ alignas(16) unsigned short pool[26624];   // 52 KB
    unsigned short* Qs = pool;            // [64][136] bf16
    unsigned short* Ks = pool + 8704;     // [64][136] bf16
    unsigned short* Vt = pool + 17408;    // [128][72] bf16 (V transposed)
    unsigned short* Ps = pool + w * 1152; // per-wave [16][72], overlays Qs
    float* Os = (float*)pool;             // [64][132] fp32 (epilogue overlay)

    const size_t gbase = (size_t)by * ((size_t)Tn * Hn);

    // ---- stage Q tile ----
    {
        const unsigned short* src = Qb + gbase + (size_t)(qt * 64) * Hn;
#pragma unroll
        for (int i = 0; i < 4; ++i) {
            int idx = t + i * 256;
            int row = idx >> 4, col = (idx & 15) * 8;
            *(uint4*)&Qs[row * 136 + col] = *(const uint4*)&src[row * 128 + col];
        }
    }
    __syncthreads();

    // hoist Q B-frags (Q^T): lane holds Q[q=l16][d=ks*32+quad*8+j]
    bf16x8 qf[4];
#pragma unroll
    for (int ks = 0; ks < 4; ++ks)
        qf[ks] = *(const bf16x8*)&Qs[(w * 16 + l16) * 136 + ks * 32 + quad * 8];

    f32x4 acc_o[8];
#pragma unroll
    for (int i = 0; i < 8; ++i) acc_o[i] = (f32x4){0.f, 0.f, 0.f, 0.f};
    float m_run = -1e30f, l_run = 0.f;

    for (int kt = 0; kt <= qt; ++kt) {
        __syncthreads();   // also separates pre-loop Q-frag reads from Ps writes
        {
            // stage K (row-major)
            const unsigned short* ksrc = Kb + gbase + (size_t)(kt * 64) * Hn;
#pragma unroll
            for (int i = 0; i < 4; ++i) {
                int idx = t + i * 256;
                int row = idx >> 4, col = (idx & 15) * 8;
                *(uint4*)&Ks[row * 136 + col] = *(const uint4*)&ksrc[row * 128 + col];
            }
            // stage V transposed: Vt[d][s], paired-s b32 writes (conflict-free)
            const unsigned short* vsrc = Vb + gbase + (size_t)(kt * 64) * Hn;
            int s0 = (t & 31) * 2, d0 = (t >> 5) * 16;
            uint4 ra = *(const uint4*)&vsrc[s0 * 128 + d0];
            uint4 rb = *(const uint4*)&vsrc[s0 * 128 + d0 + 8];
            uint4 rc = *(const uint4*)&vsrc[(s0 + 1) * 128 + d0];
            uint4 rd = *(const uint4*)&vsrc[(s0 + 1) * 128 + d0 + 8];
            const unsigned short* pa = (const unsigned short*)&ra;
            const unsigned short* pb = (const unsigned short*)&rb;
            const unsigned short* pc = (const unsigned short*)&rc;
            const unsigned short* pd = (const unsigned short*)&rd;
#pragma unroll
            for (int dd = 0; dd < 8; ++dd)
                *(unsigned int*)&Vt[(d0 + dd) * 72 + s0] =
                    (unsigned int)pa[dd] | ((unsigned int)pc[dd] << 16);
#pragma unroll
            for (int dd = 0; dd < 8; ++dd)
                *(unsigned int*)&Vt[(d0 + 8 + dd) * 72 + s0] =
                    (unsigned int)pb[dd] | ((unsigned int)pd[dd] << 16);
        }
        __syncthreads();

        const bool diag = (kt == qt);
        // S^T = K.Q^T ; lane holds S[q=l16][s=st*16+quad*4+r]
        f32x4 sa[4];
#pragma unroll
        for (int st = 0; st < 4; ++st) {
            if (diag && st > w) {
                sa[st] = (f32x4){-1e30f, -1e30f, -1e30f, -1e30f};  // fully masked
            } else {
                f32x4 c = (f32x4){0.f, 0.f, 0.f, 0.f};
#pragma unroll
                for (int ks = 0; ks < 4; ++ks) {
                    bf16x8 kf = *(const bf16x8*)&Ks[(st * 16 + l16) * 136 + ks * 32 + quad * 8];
                    c = __builtin_amdgcn_mfma_f32_16x16x32_bf16(kf, qf[ks], c, 0, 0, 0);
                }
                if (diag && st == w) {
#pragma unroll
                    for (int r = 0; r < 4; ++r)
                        if (quad * 4 + r > l16) c[r] = -1e30f;
                }
                sa[st] = c;
            }
        }

        // online softmax for q-row l16 (state replicated across the 4 quads)
        float mloc = -1e30f;
#pragma unroll
        for (int st = 0; st < 4; ++st)
#pragma unroll
            for (int r = 0; r < 4; ++r) mloc = fmaxf(mloc, sa[st][r]);
        mloc = fmaxf(mloc, __shfl_xor(mloc, 16));
        mloc = fmaxf(mloc, __shfl_xor(mloc, 32));
        const float m_new = fmaxf(m_run, mloc);
        const float alpha = __expf(m_run - m_new);
        float p[4][4];
        float lsum = 0.f;
#pragma unroll
        for (int st = 0; st < 4; ++st)
#pragma unroll
            for (int r = 0; r < 4; ++r) {
                p[st][r] = __expf(sa[st][r] - m_new);
                lsum += p[st][r];
            }
        lsum += __shfl_xor(lsum, 16);
        lsum += __shfl_xor(lsum, 32);
        l_run = l_run * alpha + lsum;
        m_run = m_new;
#pragma unroll
        for (int i = 0; i < 8; ++i) acc_o[i] *= alpha;

        // P (C-layout) -> per-wave LDS -> P^T B-frags (same-wave, no barrier)
#pragma unroll
        for (int st = 0; st < 4; ++st) {
            uint2 pk;
            pk.x = (unsigned int)f2bf(p[st][0]) | ((unsigned int)f2bf(p[st][1]) << 16);
            pk.y = (unsigned int)f2bf(p[st][2]) | ((unsigned int)f2bf(p[st][3]) << 16);
            *(uint2*)&Ps[l16 * 72 + st * 16 + quad * 4] = pk;
        }
        bf16x8 pf0 = *(const bf16x8*)&Ps[l16 * 72 + quad * 8];
        bf16x8 pf1 = *(const bf16x8*)&Ps[l16 * 72 + 32 + quad * 8];

        // O^T += V^T . P^T
#pragma unroll
        for (int dt = 0; dt < 8; ++dt) {
            bf16x8 vf0 = *(const bf16x8*)&Vt[(dt * 16 + l16) * 72 + quad * 8];
            acc_o[dt] = __builtin_amdgcn_mfma_f32_16x16x32_bf16(vf0, pf0, acc_o[dt], 0, 0, 0);
            bf16x8 vf1 = *(const bf16x8*)&Vt[(dt * 16 + l16) * 72 + 32 + quad * 8];
            acc_o[dt] = __builtin_amdgcn_mfma_f32_16x16x32_bf16(vf1, pf1, acc_o[dt], 0, 0, 0);
        }
    }

    // epilogue: O^T regs -> LDS (transpose) -> coalesced fp32 stores
    __syncthreads();
    const float inv = 1.f / l_run;
#pragma unroll
    for (int dt = 0; dt < 8; ++dt) {
        f32x4 v = acc_o[dt] * inv;
        *(f32x4*)&Os[(w * 16 + l16) * 132 + dt * 16 + quad * 4] = v;
    }
    __syncthreads();
    float* dst = out + gbase + (size_t)(qt * 64) * Hn;
#pragma unroll
    for (int i = 0; i < 8; ++i) {
        int idx = (t + i * 256) * 4;
        int row = idx >> 7, col = idx & 127;
        *(float4*)&dst[row * 128 + col] = *(const float4*)&Os[row * 132 + col];
    }
}

// ---------------------------------------------------------------------------
extern "C" void kernel_launch(void* const* d_in, const int* in_sizes, int n_in,
                              void* d_out, int out_size, void* d_ws, size_t ws_size,
                              hipStream_t stream) {
    const float* x  = (const float*)d_in[0];
    const float* Wq = (const float*)d_in[1];
    const float* Wk = (const float*)d_in[2];
    const float* Wv = (const float*)d_in[3];
    float* o = (float*)d_out;            // output fp32 (verified round 4)

    unsigned short* Qb = (unsigned short*)d_ws;                 // (B*T, H) bf16
    unsigned short* Kb = Qb + (size_t)Bn * Tn * Hn;
    unsigned short* Vb = Kb + (size_t)Bn * Tn * Hn;

    qkv_mfma<<<dim3(3, 256), 256, 0, stream>>>(x, Wq, Wk, Wv, Qb, Kb, Vb);
    flash_mfma<<<dim3(64, 8), 256, 0, stream>>>(Qb, Kb, Vb, o);
}

// Round 8
// 435.987 us; speedup vs baseline: 10.7692x; 1.0572x over previous
//
#include <hip/hip_runtime.h>
#include <hip/hip_bf16.h>
#include <stdint.h>

#define Bn 8
#define Tn 4096
#define En 1024
#define Hn 128
#define SCALE 0.08838834764831845f  // 1/sqrt(128)

typedef __attribute__((ext_vector_type(8))) short bf16x8;
typedef __attribute__((ext_vector_type(4))) float f32x4;

__device__ __forceinline__ float bf2f(unsigned short v) {
    return __uint_as_float(((unsigned int)v) << 16);
}
// RNE pack of two fp32 -> packed bf16x2 (v_cvt_pk_bf16_f32 on gfx950)
__device__ __forceinline__ unsigned int pkbf(float a, float b) {
    __hip_bfloat162 h = __float22bfloat162_rn(make_float2(a, b));
    union { __hip_bfloat162 h2; unsigned int u; } cv;
    cv.h2 = h;
    return cv.u;
}

// ---------------------------------------------------------------------------
// QKV projection via MFMA, software-pipelined staging.
// grid (256, 3): x = 128-row M tile, y = which {Q,K,V}. Same-mt triplet ->
// same linear-id mod-256 slot -> same CU/XCD: x tile read once from HBM.
// block 256 = 4 waves; wave owns 32 rows. BK=64. LDS 36 KB.
// ---------------------------------------------------------------------------
__global__ __launch_bounds__(256)
void qkv_mfma(const float* __restrict__ x,
              const float* __restrict__ Wq,
              const float* __restrict__ Wk,
              const float* __restrict__ Wv,
              unsigned short* __restrict__ Qo,
              unsigned short* __restrict__ Ko,
              unsigned short* __restrict__ Vo) {
    const int mt = blockIdx.x;
    const int which = blockIdx.y;
    const float* W = (which == 0) ? Wq : (which == 1) ? Wk : Wv;
    unsigned short* out = (which == 0) ? Qo : (which == 1) ? Ko : Vo;
    const float scale = (which == 0) ? SCALE : 1.0f;

    __shared__ alignas(16) unsigned short Xs[128 * 72];  // [m][k] bf16, pad 72
    __shared__ alignas(16) unsigned short Wt[128 * 72];  // [n][k] bf16 (transposed)

    const int t = threadIdx.x;
    const int w = t >> 6;
    const int lane = t & 63;
    const int quad = lane >> 4;
    const int l16 = lane & 15;

    // staging coords
    const int xrow = t >> 1;              // 0..127
    const int xkc = (t & 1) * 32;         // 0 or 32
    const int ws0 = (t & 31) * 2;         // k pair 0..62
    const int wd0 = (t >> 5) * 16;        // n group 0..112

    const float* xsrc0 = x + (size_t)(mt * 128 + xrow) * En + xkc;

    f32x4 acc[2][8];
#pragma unroll
    for (int mi = 0; mi < 2; ++mi)
#pragma unroll
        for (int nst = 0; nst < 8; ++nst) acc[mi][nst] = (f32x4){0.f, 0.f, 0.f, 0.f};

    // ---- prefetch tile 0 ----
    float4 xpre[8], wpre[8];
    {
        const float* src = xsrc0;
#pragma unroll
        for (int i = 0; i < 8; ++i) xpre[i] = *(const float4*)(src + i * 4);
        const float* w0 = W + (size_t)ws0 * Hn + wd0;
        const float* w1 = w0 + Hn;
#pragma unroll
        for (int i = 0; i < 4; ++i) wpre[i] = *(const float4*)(w0 + i * 4);
#pragma unroll
        for (int i = 0; i < 4; ++i) wpre[4 + i] = *(const float4*)(w1 + i * 4);
    }

    for (int kt = 0; kt < 16; ++kt) {
        __syncthreads();
        // ---- write staged regs -> LDS (cvt fp32->bf16) ----
        {
            unsigned int u[16];
#pragma unroll
            for (int i = 0; i < 8; ++i) {
                u[2 * i]     = pkbf(xpre[i].x, xpre[i].y);
                u[2 * i + 1] = pkbf(xpre[i].z, xpre[i].w);
            }
#pragma unroll
            for (int i = 0; i < 4; ++i)
                *(uint4*)&Xs[xrow * 72 + xkc + i * 8] = ((const uint4*)u)[i];

            const float* ax = (const float*)&wpre[0];
            const float* bx = (const float*)&wpre[4];
#pragma unroll
            for (int dd = 0; dd < 16; ++dd)
                *(unsigned int*)&Wt[(wd0 + dd) * 72 + ws0] = pkbf(ax[dd], bx[dd]);
        }
        // ---- issue next tile's global loads ----
        if (kt < 15) {
            const float* src = xsrc0 + (kt + 1) * 64;
#pragma unroll
            for (int i = 0; i < 8; ++i) xpre[i] = *(const float4*)(src + i * 4);
            const float* w0 = W + (size_t)((kt + 1) * 64 + ws0) * Hn + wd0;
            const float* w1 = w0 + Hn;
#pragma unroll
            for (int i = 0; i < 4; ++i) wpre[i] = *(const float4*)(w0 + i * 4);
#pragma unroll
            for (int i = 0; i < 4; ++i) wpre[4 + i] = *(const float4*)(w1 + i * 4);
        }
        __syncthreads();

        // ---- MFMA: 32 per wave per k-tile ----
#pragma unroll
        for (int ks = 0; ks < 2; ++ks) {
            bf16x8 af[2];
#pragma unroll
            for (int mi = 0; mi < 2; ++mi)
                af[mi] = *(const bf16x8*)&Xs[(w * 32 + mi * 16 + l16) * 72 + ks * 32 + quad * 8];
#pragma unroll
            for (int nst = 0; nst < 8; ++nst) {
                bf16x8 bfr = *(const bf16x8*)&Wt[(nst * 16 + l16) * 72 + ks * 32 + quad * 8];
                acc[0][nst] = __builtin_amdgcn_mfma_f32_16x16x32_bf16(bfr, af[0], acc[0][nst], 0, 0, 0);
                acc[1][nst] = __builtin_amdgcn_mfma_f32_16x16x32_bf16(bfr, af[1], acc[1][nst], 0, 0, 0);
            }
        }
    }

    // ---- epilogue: lane holds m = l16, n = nst*16 + quad*4 + r ----
#pragma unroll
    for (int mi = 0; mi < 2; ++mi) {
        const size_t rowbase = (size_t)(mt * 128 + w * 32 + mi * 16 + l16) * Hn;
#pragma unroll
        for (int nst = 0; nst < 8; ++nst) {
            f32x4 v = acc[mi][nst];
            uint2 pk;
            pk.x = pkbf(v[0] * scale, v[1] * scale);
            pk.y = pkbf(v[2] * scale, v[3] * scale);
            *(uint2*)(out + rowbase + nst * 16 + quad * 4) = pk;
        }
    }
}

// ---------------------------------------------------------------------------
// MFMA flash attention, software-pipelined staging.
// grid (8, 64): x = batch (-> XCD = batch: K/V working set 2.1 MB fits L2),
// y = bx with qt = bx<32 ? 63-bx : bx-32 (CU pairs c,c+32 sum to 63).
// block 256 (4 waves); wave w owns q-rows w*16..+15. LDS 52 KB.
// ---------------------------------------------------------------------------
__global__ __launch_bounds__(256)
void flash_mfma(const unsigned short* __restrict__ Qb,
                const unsigned short* __restrict__ Kb,
                const unsigned short* __restrict__ Vb,
                float* __restrict__ out) {
    const int b = blockIdx.x;                     // batch
    const int bx = blockIdx.y;
    const int qt = (bx < 32) ? (63 - bx) : (bx - 32);
    const int t = threadIdx.x;
    const int w = t >> 6;
    const int lane = t & 63;
    const int quad = lane >> 4;
    const int l16 = lane & 15;

    __shared__ alignas(16) unsigned short pool[26624];   // 52 KB
    unsigned short* Qs = pool;            // [64][136] bf16
    unsigned short* Ks = pool + 8704;     // [64][136] bf16
    unsigned short* Vt = pool + 17408;    // [128][72] bf16 (V transposed)
    unsigned short* Ps = pool + w * 1152; // per-wave [16][72], overlays Qs
    float* Os = (float*)pool;             // [64][132] fp32 (epilogue overlay)

    const size_t gbase = (size_t)b * ((size_t)Tn * Hn);
    const unsigned short* kbase = Kb + gbase;
    const unsigned short* vbase = Vb + gbase;

    // staging coords (K: row-major; V: transpose-pairs)
    const int krow0 = t >> 4;             // + 16*i
    const int kcol = (t & 15) * 8;
    const int vs0 = (t & 31) * 2;
    const int vd0 = (t >> 5) * 16;

    // ---- stage Q tile ----
    {
        const unsigned short* src = Qb + gbase + (size_t)(qt * 64) * Hn;
#pragma unroll
        for (int i = 0; i < 4; ++i)
            *(uint4*)&Qs[(krow0 + 16 * i) * 136 + kcol] =
                *(const uint4*)&src[(krow0 + 16 * i) * 128 + kcol];
    }
    __syncthreads();

    // hoist Q B-frags (Q^T): lane holds Q[q=l16][d=ks*32+quad*8+j]
    bf16x8 qf[4];
#pragma unroll
    for (int ks = 0; ks < 4; ++ks)
        qf[ks] = *(const bf16x8*)&Qs[(w * 16 + l16) * 136 + ks * 32 + quad * 8];

    f32x4 acc_o[8];
#pragma unroll
    for (int i = 0; i < 8; ++i) acc_o[i] = (f32x4){0.f, 0.f, 0.f, 0.f};
    float m_run = -1e30f, l_run = 0.f;

    // ---- prefetch tile 0 ----
    uint4 kpre[4], vra, vrb, vrc, vrd;
    {
        const unsigned short* ksrc = kbase;
#pragma unroll
        for (int i = 0; i < 4; ++i)
            kpre[i] = *(const uint4*)&ksrc[(krow0 + 16 * i) * 128 + kcol];
        const unsigned short* vsrc = vbase;
        vra = *(const uint4*)&vsrc[vs0 * 128 + vd0];
        vrb = *(const uint4*)&vsrc[vs0 * 128 + vd0 + 8];
        vrc = *(const uint4*)&vsrc[(vs0 + 1) * 128 + vd0];
        vrd = *(const uint4*)&vsrc[(vs0 + 1) * 128 + vd0 + 8];
    }

    for (int kt = 0; kt <= qt; ++kt) {
        __syncthreads();
        // ---- write staged regs -> LDS ----
        {
#pragma unroll
            for (int i = 0; i < 4; ++i)
                *(uint4*)&Ks[(krow0 + 16 * i) * 136 + kcol] = kpre[i];
            const unsigned short* pa = (const unsigned short*)&vra;
            const unsigned short* pb = (const unsigned short*)&vrb;
            const unsigned short* pc = (const unsigned short*)&vrc;
            const unsigned short* pd = (const unsigned short*)&vrd;
#pragma unroll
            for (int dd = 0; dd < 8; ++dd)
                *(unsigned int*)&Vt[(vd0 + dd) * 72 + vs0] =
                    (unsigned int)pa[dd] | ((unsigned int)pc[dd] << 16);
#pragma unroll
            for (int dd = 0; dd < 8; ++dd)
                *(unsigned int*)&Vt[(vd0 + 8 + dd) * 72 + vs0] =
                    (unsigned int)pb[dd] | ((unsigned int)pd[dd] << 16);
        }
        // ---- issue next tile's global loads ----
        if (kt < qt) {
            const unsigned short* ksrc = kbase + (size_t)((kt + 1) * 64) * Hn;
#pragma unroll
            for (int i = 0; i < 4; ++i)
                kpre[i] = *(const uint4*)&ksrc[(krow0 + 16 * i) * 128 + kcol];
            const unsigned short* vsrc = vbase + (size_t)((kt + 1) * 64) * Hn;
            vra = *(const uint4*)&vsrc[vs0 * 128 + vd0];
            vrb = *(const uint4*)&vsrc[vs0 * 128 + vd0 + 8];
            vrc = *(const uint4*)&vsrc[(vs0 + 1) * 128 + vd0];
            vrd = *(const uint4*)&vsrc[(vs0 + 1) * 128 + vd0 + 8];
        }
        __syncthreads();

        const bool diag = (kt == qt);
        // S^T = K.Q^T ; lane holds S[q=l16][s=st*16+quad*4+r]
        f32x4 sa[4];
#pragma unroll
        for (int st = 0; st < 4; ++st) {
            if (diag && st > w) {
                sa[st] = (f32x4){-1e30f, -1e30f, -1e30f, -1e30f};  // fully masked
            } else {
                f32x4 c = (f32x4){0.f, 0.f, 0.f, 0.f};
#pragma unroll
                for (int ks = 0; ks < 4; ++ks) {
                    bf16x8 kf = *(const bf16x8*)&Ks[(st * 16 + l16) * 136 + ks * 32 + quad * 8];
                    c = __builtin_amdgcn_mfma_f32_16x16x32_bf16(kf, qf[ks], c, 0, 0, 0);
                }
                if (diag && st == w) {
#pragma unroll
                    for (int r = 0; r < 4; ++r)
                        if (quad * 4 + r > l16) c[r] = -1e30f;
                }
                sa[st] = c;
            }
        }

        // online softmax for q-row l16 (state replicated across the 4 quads)
        float mloc = -1e30f;
#pragma unroll
        for (int st = 0; st < 4; ++st)
#pragma unroll
            for (int r = 0; r < 4; ++r) mloc = fmaxf(mloc, sa[st][r]);
        mloc = fmaxf(mloc, __shfl_xor(mloc, 16));
        mloc = fmaxf(mloc, __shfl_xor(mloc, 32));
        const float m_new = fmaxf(m_run, mloc);
        const float alpha = __expf(m_run - m_new);
        float p[4][4];
        float lsum = 0.f;
#pragma unroll
        for (int st = 0; st < 4; ++st)
#pragma unroll
            for (int r = 0; r < 4; ++r) {
                p[st][r] = __expf(sa[st][r] - m_new);
                lsum += p[st][r];
            }
        lsum += __shfl_xor(lsum, 16);
        lsum += __shfl_xor(lsum, 32);
        l_run = l_run * alpha + lsum;
        m_run = m_new;
#pragma unroll
        for (int i = 0; i < 8; ++i) acc_o[i] *= alpha;

        // P (C-layout) -> per-wave LDS -> P^T B-frags (same-wave, no barrier)
#pragma unroll
        for (int st = 0; st < 4; ++st) {
            uint2 pk;
            pk.x = pkbf(p[st][0], p[st][1]);
            pk.y = pkbf(p[st][2], p[st][3]);
            *(uint2*)&Ps[l16 * 72 + st * 16 + quad * 4] = pk;
        }
        bf16x8 pf0 = *(const bf16x8*)&Ps[l16 * 72 + quad * 8];
        bf16x8 pf1 = *(const bf16x8*)&Ps[l16 * 72 + 32 + quad * 8];

        // O^T += V^T . P^T
#pragma unroll
        for (int dt = 0; dt < 8; ++dt) {
            bf16x8 vf0 = *(const bf16x8*)&Vt[(dt * 16 + l16) * 72 + quad * 8];
            acc_o[dt] = __builtin_amdgcn_mfma_f32_16x16x32_bf16(vf0, pf0, acc_o[dt], 0, 0, 0);
            bf16x8 vf1 = *(const bf16x8*)&Vt[(dt * 16 + l16) * 72 + 32 + quad * 8];
            acc_o[dt] = __builtin_amdgcn_mfma_f32_16x16x32_bf16(vf1, pf1, acc_o[dt], 0, 0, 0);
        }
    }

    // epilogue: O^T regs -> LDS (transpose) -> coalesced fp32 stores
    __syncthreads();
    const float inv = 1.f / l_run;
#pragma unroll
    for (int dt = 0; dt < 8; ++dt) {
        f32x4 v = acc_o[dt] * inv;
        *(f32x4*)&Os[(w * 16 + l16) * 132 + dt * 16 + quad * 4] = v;
    }
    __syncthreads();
    float* dst = out + gbase + (size_t)(qt * 64) * Hn;
#pragma unroll
    for (int i = 0; i < 8; ++i) {
        int idx = (t + i * 256) * 4;
        int row = idx >> 7, col = idx & 127;
        *(float4*)&dst[row * 128 + col] = *(const float4*)&Os[row * 132 + col];
    }
}

// ---------------------------------------------------------------------------
extern "C" void kernel_launch(void* const* d_in, const int* in_sizes, int n_in,
                              void* d_out, int out_size, void* d_ws, size_t ws_size,
                              hipStream_t stream) {
    const float* x  = (const float*)d_in[0];
    const float* Wq = (const float*)d_in[1];
    const float* Wk = (const float*)d_in[2];
    const float* Wv = (const float*)d_in[3];
    float* o = (float*)d_out;            // output fp32 (verified round 4)

    unsigned short* Qb = (unsigned short*)d_ws;                 // (B*T, H) bf16
    unsigned short* Kb = Qb + (size_t)Bn * Tn * Hn;
    unsigned short* Vb = Kb + (size_t)Bn * Tn * Hn;

    qkv_mfma<<<dim3(256, 3), 256, 0, stream>>>(x, Wq, Wk, Wv, Qb, Kb, Vb);
    flash_mfma<<<dim3(8, 64), 256, 0, stream>>>(Qb, Kb, Vb, o);
}